// Round 1
// baseline (239.853 us; speedup 1.0000x reference)
//
#include <hip/hip_runtime.h>

#define EPS 0.01f
#define B_ 8
#define T_ 4096
#define D_ 1024

// ---------------- Kernel 1: gate prefix counts -> alpha weights ----------------
// alpha[b,t] = g ? EPS * (1-EPS)^(C_b - c_{b,t}) : 0
// where g = (!pad && upd), c = inclusive gated count, C_b = total gated count.
__global__ void gate_alpha_kernel(const int* __restrict__ pad,
                                  const int* __restrict__ upd,
                                  float* __restrict__ alpha) {
    const int b = blockIdx.x;
    const int tid = threadIdx.x;            // 0..255
    const int CH = T_ / 256;                // 16 t's per thread
    const int base = b * T_;
    const int t0 = tid * CH;

    int g[16];
    int cnt = 0;
    #pragma unroll
    for (int i = 0; i < CH; ++i) {
        int t = t0 + i;
        int gi = (pad[base + t] == 0 && upd[base + t] != 0) ? 1 : 0;
        g[i] = gi;
        cnt += gi;
    }

    __shared__ int s[256];
    s[tid] = cnt;
    __syncthreads();
    // Hillis-Steele inclusive scan over per-thread counts
    for (int off = 1; off < 256; off <<= 1) {
        int v = s[tid];
        int add = (tid >= off) ? s[tid - off] : 0;
        __syncthreads();
        s[tid] = v + add;
        __syncthreads();
    }
    const int total = s[255];
    const int excl = s[tid] - cnt;

    const float L = -0.014499569695115089f;  // log2(0.99)
    int c = excl;
    #pragma unroll
    for (int i = 0; i < CH; ++i) {
        int t = t0 + i;
        c += g[i];
        float a = 0.f;
        if (g[i]) a = EPS * exp2f((float)(total - c) * L);
        alpha[base + t] = a;
    }
}

// ---------------- Kernel 2: fused y = x@w  and  mem += alpha*x ----------------
// One wave per row (b,t). Lane covers 16 d's in 4 contiguous float4 groups:
// d = k*256 + lane*4 + j  (per-instruction fully coalesced 1KB segments).
#define TCHUNK 128
__global__ __launch_bounds__(1024) void main_pass_kernel(
    const float* __restrict__ x, const float* __restrict__ w,
    const float* __restrict__ alpha, float* __restrict__ y,
    float* __restrict__ mem) {
    const int b = blockIdx.y;
    const int tbase = blockIdx.x * TCHUNK;
    const int tid = threadIdx.x;           // 0..1023
    const int wave = tid >> 6;             // 0..15
    const int lane = tid & 63;

    float4 wv[4];
    #pragma unroll
    for (int k = 0; k < 4; ++k)
        wv[k] = *reinterpret_cast<const float4*>(w + k * 256 + lane * 4);

    float4 acc[4];
    #pragma unroll
    for (int k = 0; k < 4; ++k) acc[k] = make_float4(0.f, 0.f, 0.f, 0.f);

    for (int r = wave; r < TCHUNK; r += 16) {
        const int t = tbase + r;
        const float* row = x + ((size_t)b * T_ + t) * D_;
        const float al = alpha[b * T_ + t];
        float dot = 0.f;
        #pragma unroll
        for (int k = 0; k < 4; ++k) {
            float4 v = *reinterpret_cast<const float4*>(row + k * 256 + lane * 4);
            dot += v.x * wv[k].x + v.y * wv[k].y + v.z * wv[k].z + v.w * wv[k].w;
            acc[k].x += al * v.x;
            acc[k].y += al * v.y;
            acc[k].z += al * v.z;
            acc[k].w += al * v.w;
        }
        #pragma unroll
        for (int off = 32; off >= 1; off >>= 1)
            dot += __shfl_xor(dot, off);
        if (lane == 0) y[b * T_ + t] = dot;
    }

    // Reduce per-wave mem partials across the block, then one global atomic set.
    __shared__ float mem_s[D_];
    for (int i = tid; i < D_; i += 1024) mem_s[i] = 0.f;
    __syncthreads();
    #pragma unroll
    for (int k = 0; k < 4; ++k) {
        const int d = k * 256 + lane * 4;
        atomicAdd(&mem_s[d + 0], acc[k].x);
        atomicAdd(&mem_s[d + 1], acc[k].y);
        atomicAdd(&mem_s[d + 2], acc[k].z);
        atomicAdd(&mem_s[d + 3], acc[k].w);
    }
    __syncthreads();
    for (int i = tid; i < D_; i += 1024)
        atomicAdd(&mem[b * D_ + i], mem_s[i]);
}

// ---------------- Kernel 3: affine scan over t -> bias ----------------
// s_t = a_t * s_{t-1} + u_t,  a_t = 1-EPS*g_t, u_t = EPS*g_t*y_t
// bias[b,t] = pad ? 1 : clip(1 + tanh(s_t), 0.8, 1.2)
__global__ void scan_bias_kernel(const float* __restrict__ y,
                                 const int* __restrict__ pad,
                                 const int* __restrict__ upd,
                                 float* __restrict__ bias) {
    const int b = blockIdx.x;
    const int tid = threadIdx.x;            // 0..255
    const int CH = T_ / 256;                // 16
    const int base = b * T_;
    const int t0 = tid * CH;

    float av[16], uv[16];
    float a_c = 1.f, u_c = 0.f;
    #pragma unroll
    for (int i = 0; i < CH; ++i) {
        int t = t0 + i;
        int g = (pad[base + t] == 0 && upd[base + t] != 0) ? 1 : 0;
        float a = g ? (1.f - EPS) : 1.f;
        float u = g ? EPS * y[base + t] : 0.f;
        av[i] = a; uv[i] = u;
        u_c = a * u_c + u;   // compose: apply previous, then this step
        a_c = a * a_c;
    }

    __shared__ float As[256], Us[256];
    As[tid] = a_c; Us[tid] = u_c;
    __syncthreads();
    // Hillis-Steele inclusive scan with affine composition (A1,U1) then (A2,U2)
    for (int off = 1; off < 256; off <<= 1) {
        float A2 = As[tid], U2 = Us[tid];
        float A1 = (tid >= off) ? As[tid - off] : 1.f;
        float U1 = (tid >= off) ? Us[tid - off] : 0.f;
        __syncthreads();
        As[tid] = A1 * A2;
        Us[tid] = A2 * U1 + U2;
        __syncthreads();
    }
    float s = (tid > 0) ? Us[tid - 1] : 0.f;   // state entering this chunk

    #pragma unroll
    for (int i = 0; i < CH; ++i) {
        int t = t0 + i;
        s = av[i] * s + uv[i];
        float bval;
        if (pad[base + t] != 0) {
            bval = 1.f;
        } else {
            bval = 1.f + tanhf(s);
            bval = fminf(fmaxf(bval, 0.8f), 1.2f);
        }
        bias[base + t] = bval;
    }
}

extern "C" void kernel_launch(void* const* d_in, const int* in_sizes, int n_in,
                              void* d_out, int out_size, void* d_ws, size_t ws_size,
                              hipStream_t stream) {
    const float* x  = (const float*)d_in[0];   // write_signal (B,T,D) f32
    const int* pad  = (const int*)d_in[1];     // pad_mask (B,T)
    const int* upd  = (const int*)d_in[2];     // update_mask (B,T)
    const float* w  = (const float*)d_in[3];   // (D,) f32

    float* out  = (float*)d_out;
    float* bias = out;                 // B*T floats
    float* mem  = out + B_ * T_;       // B*D floats

    float* alpha = (float*)d_ws;       // B*T floats
    float* y     = alpha + B_ * T_;    // B*T floats

    hipMemsetAsync(mem, 0, B_ * D_ * sizeof(float), stream);
    gate_alpha_kernel<<<B_, 256, 0, stream>>>(pad, upd, alpha);
    dim3 grid2(T_ / TCHUNK, B_);
    main_pass_kernel<<<grid2, 1024, 0, stream>>>(x, w, alpha, y, mem);
    scan_bias_kernel<<<B_, 256, 0, stream>>>(y, pad, upd, bias);
}

// Round 2
// 188.284 us; speedup vs baseline: 1.2739x; 1.2739x over previous
//
#include <hip/hip_runtime.h>

#define EPS 0.01f
#define B_ 8
#define T_ 4096
#define D_ 1024

// ---------------- Kernel 1: gate prefix counts -> alpha weights ----------------
// alpha[b,t] = g ? EPS * (1-EPS)^(C_b - c_{b,t}) : 0
// 1024 threads, 4 t's per thread via one int4 load each (fully coalesced).
__global__ __launch_bounds__(1024) void gate_alpha_kernel(
    const int* __restrict__ pad, const int* __restrict__ upd,
    float* __restrict__ alpha) {
    const int b = blockIdx.x;
    const int tid = threadIdx.x;            // 0..1023
    const int base = b * T_;

    const int4 pv = reinterpret_cast<const int4*>(pad + base)[tid];
    const int4 uv = reinterpret_cast<const int4*>(upd + base)[tid];
    int g[4];
    g[0] = (pv.x == 0 && uv.x != 0) ? 1 : 0;
    g[1] = (pv.y == 0 && uv.y != 0) ? 1 : 0;
    g[2] = (pv.z == 0 && uv.z != 0) ? 1 : 0;
    g[3] = (pv.w == 0 && uv.w != 0) ? 1 : 0;
    const int cnt = g[0] + g[1] + g[2] + g[3];

    __shared__ int s[1024];
    s[tid] = cnt;
    __syncthreads();
    for (int off = 1; off < 1024; off <<= 1) {
        int v = s[tid];
        int add = (tid >= off) ? s[tid - off] : 0;
        __syncthreads();
        s[tid] = v + add;
        __syncthreads();
    }
    const int total = s[1023];
    int c = s[tid] - cnt;                    // exclusive count entering this thread

    const float L = -0.014499569695115089f;  // log2(0.99)
    float4 av;
    float* ap = &av.x;
    #pragma unroll
    for (int i = 0; i < 4; ++i) {
        c += g[i];
        ap[i] = g[i] ? EPS * exp2f((float)(total - c) * L) : 0.f;
    }
    reinterpret_cast<float4*>(alpha + base)[tid] = av;
}

// ---------------- Kernel 2: fused y = x@w and per-block mem partials ----------
// One wave per gated row; non-gated rows are skipped entirely (wave-uniform).
#define TCHUNK 128
#define NBLK_T (T_ / TCHUNK)   // 32
__global__ __launch_bounds__(1024) void main_pass_kernel(
    const float* __restrict__ x, const float* __restrict__ w,
    const float* __restrict__ alpha, float* __restrict__ y,
    float* __restrict__ mem_part) {
    const int b = blockIdx.y;
    const int tbase = blockIdx.x * TCHUNK;
    const int tid = threadIdx.x;           // 0..1023
    const int wave = tid >> 6;             // 0..15
    const int lane = tid & 63;

    float4 wv[4];
    #pragma unroll
    for (int k = 0; k < 4; ++k)
        wv[k] = *reinterpret_cast<const float4*>(w + k * 256 + lane * 4);

    float4 acc[4];
    #pragma unroll
    for (int k = 0; k < 4; ++k) acc[k] = make_float4(0.f, 0.f, 0.f, 0.f);

    for (int r = wave; r < TCHUNK; r += 16) {
        const int t = tbase + r;
        const float al = alpha[b * T_ + t];
        if (al == 0.f) continue;           // non-gated row: no data needed
        const float* row = x + ((size_t)b * T_ + t) * D_;
        float dot = 0.f;
        #pragma unroll
        for (int k = 0; k < 4; ++k) {
            float4 v = *reinterpret_cast<const float4*>(row + k * 256 + lane * 4);
            dot += v.x * wv[k].x + v.y * wv[k].y + v.z * wv[k].z + v.w * wv[k].w;
            acc[k].x += al * v.x;
            acc[k].y += al * v.y;
            acc[k].z += al * v.z;
            acc[k].w += al * v.w;
        }
        #pragma unroll
        for (int off = 32; off >= 1; off >>= 1)
            dot += __shfl_xor(dot, off);
        if (lane == 0) y[b * T_ + t] = dot;
    }

    // Block-level reduction of mem partials: [wave][d] layout, then each
    // thread sums one d over the 16 waves (conflict-free column reads).
    __shared__ float part[16][D_];         // 64 KiB
    #pragma unroll
    for (int k = 0; k < 4; ++k)
        *reinterpret_cast<float4*>(&part[wave][k * 256 + lane * 4]) = acc[k];
    __syncthreads();
    float sum = 0.f;
    #pragma unroll
    for (int w2 = 0; w2 < 16; ++w2) sum += part[w2][tid];
    mem_part[((size_t)b * NBLK_T + blockIdx.x) * D_ + tid] = sum;
}

// ---------------- Kernel 2b: reduce per-block partials -> mem ----------------
__global__ __launch_bounds__(1024) void mem_reduce_kernel(
    const float* __restrict__ mem_part, float* __restrict__ mem) {
    const int b = blockIdx.x;
    const int d = threadIdx.x;
    float sum = 0.f;
    #pragma unroll
    for (int i = 0; i < NBLK_T; ++i)
        sum += mem_part[((size_t)b * NBLK_T + i) * D_ + d];
    mem[b * D_ + d] = sum;
}

// ---------------- Kernel 3: affine scan over t -> bias ----------------
// s_t = a_t * s_{t-1} + u_t,  a_t = 1-EPS*g_t, u_t = EPS*g_t*y_t
// bias[b,t] = pad ? 1 : clip(1 + tanh(s_t), 0.8, 1.2)
__global__ __launch_bounds__(1024) void scan_bias_kernel(
    const float* __restrict__ y, const int* __restrict__ pad,
    const int* __restrict__ upd, float* __restrict__ bias) {
    const int b = blockIdx.x;
    const int tid = threadIdx.x;            // 0..1023
    const int base = b * T_;

    const int4 pv = reinterpret_cast<const int4*>(pad + base)[tid];
    const int4 uv = reinterpret_cast<const int4*>(upd + base)[tid];
    const float4 yv = reinterpret_cast<const float4*>(y + base)[tid];
    int g[4];
    g[0] = (pv.x == 0 && uv.x != 0) ? 1 : 0;
    g[1] = (pv.y == 0 && uv.y != 0) ? 1 : 0;
    g[2] = (pv.z == 0 && uv.z != 0) ? 1 : 0;
    g[3] = (pv.w == 0 && uv.w != 0) ? 1 : 0;
    const float yl[4] = {yv.x, yv.y, yv.z, yv.w};

    float av[4], uvv[4];
    float a_c = 1.f, u_c = 0.f;
    #pragma unroll
    for (int i = 0; i < 4; ++i) {
        float a = g[i] ? (1.f - EPS) : 1.f;
        float u = g[i] ? EPS * yl[i] : 0.f;   // y is poison where !g — never used
        av[i] = a; uvv[i] = u;
        u_c = a * u_c + u;
        a_c = a * a_c;
    }

    __shared__ float As[1024], Us[1024];
    As[tid] = a_c; Us[tid] = u_c;
    __syncthreads();
    for (int off = 1; off < 1024; off <<= 1) {
        float A2 = As[tid], U2 = Us[tid];
        float A1 = (tid >= off) ? As[tid - off] : 1.f;
        float U1 = (tid >= off) ? Us[tid - off] : 0.f;
        __syncthreads();
        As[tid] = A1 * A2;
        Us[tid] = A2 * U1 + U2;
        __syncthreads();
    }
    float s = (tid > 0) ? Us[tid - 1] : 0.f;   // state entering this thread

    const int pl[4] = {pv.x, pv.y, pv.z, pv.w};
    float4 bv;
    float* bp = &bv.x;
    #pragma unroll
    for (int i = 0; i < 4; ++i) {
        s = av[i] * s + uvv[i];
        float bval;
        if (pl[i] != 0) {
            bval = 1.f;
        } else {
            bval = 1.f + tanhf(s);
            bval = fminf(fmaxf(bval, 0.8f), 1.2f);
        }
        bp[i] = bval;
    }
    reinterpret_cast<float4*>(bias + base)[tid] = bv;
}

extern "C" void kernel_launch(void* const* d_in, const int* in_sizes, int n_in,
                              void* d_out, int out_size, void* d_ws, size_t ws_size,
                              hipStream_t stream) {
    const float* x  = (const float*)d_in[0];   // write_signal (B,T,D) f32
    const int* pad  = (const int*)d_in[1];     // pad_mask (B,T)
    const int* upd  = (const int*)d_in[2];     // update_mask (B,T)
    const float* w  = (const float*)d_in[3];   // (D,) f32

    float* out  = (float*)d_out;
    float* bias = out;                 // B*T floats
    float* mem  = out + B_ * T_;       // B*D floats

    float* alpha    = (float*)d_ws;             // B*T floats
    float* y        = alpha + B_ * T_;          // B*T floats
    float* mem_part = y + B_ * T_;              // B*NBLK_T*D floats (1 MiB)

    gate_alpha_kernel<<<B_, 1024, 0, stream>>>(pad, upd, alpha);
    dim3 grid2(NBLK_T, B_);
    main_pass_kernel<<<grid2, 1024, 0, stream>>>(x, w, alpha, y, mem_part);
    mem_reduce_kernel<<<B_, 1024, 0, stream>>>(mem_part, mem);
    scan_bias_kernel<<<B_, 1024, 0, stream>>>(y, pad, upd, bias);
}